// Round 7
// baseline (390.530 us; speedup 1.0000x reference)
//
#include <hip/hip_runtime.h>
#include <hip/hip_bf16.h>
#include <math.h>
#include <stdint.h>

typedef __bf16 bf16_t;
typedef __bf16 bf16x8 __attribute__((ext_vector_type(8)));
typedef float  f32x4  __attribute__((ext_vector_type(4)));

#define BATCH   4096
#define DM      1024
#define DFF     2048
#define NTILES  8
#define MAXXB   40   // max compacted x-blocks: 32 + 7 partials

__device__ __forceinline__ float gelu_exact(float x) {
    return 0.5f * x * (1.0f + erff(x * 0.70710678118654752440f));
}

__device__ __forceinline__ void async_ld16(const bf16_t* g, bf16_t* l) {
    __builtin_amdgcn_global_load_lds(
        (const __attribute__((address_space(1))) void*)g,
        (__attribute__((address_space(3))) void*)l, 16, 0, 0);
}

__device__ __forceinline__ f32x4 mfma16(bf16x8 a, bf16x8 b, f32x4 c) {
    return __builtin_amdgcn_mfma_f32_16x16x32_bf16(a, b, c, 0, 0, 0);
}

// ---------------- 64x64 transpose+convert tile (round-1-proven math) ----------------
template<bool LO>
__device__ void tconv64_body(const float* __restrict__ src, bf16_t* __restrict__ outh,
                             bf16_t* __restrict__ outl, int K, int N, int kt, int nt,
                             float4* t /* 64*16 float4 = 16KB */, int tid) {
    const int k0 = kt * 64, n0 = nt * 64;
#pragma unroll
    for (int p = 0; p < 4; ++p) {
        int row = p * 16 + (tid >> 4);
        int c = tid & 15;
        float4 v = *(const float4*)(src + (size_t)(k0 + row) * N + n0 + c * 4);
        t[row * 16 + (c ^ ((row >> 2) & 15))] = v;
    }
    __syncthreads();
    const int n = tid >> 2, b = tid & 3;
    const float* tf = (const float*)t;
    float v[16];
#pragma unroll
    for (int i = 0; i < 16; ++i) {
        int k = 16 * b + i;
        int f4 = k * 16 + ((n >> 2) ^ ((k >> 2) & 15));
        v[i] = tf[f4 * 4 + (n & 3)];
    }
    bf16x8 h0, h1;
#pragma unroll
    for (int i = 0; i < 8; ++i) { h0[i] = (bf16_t)v[i]; h1[i] = (bf16_t)v[8 + i]; }
    size_t oi = (size_t)(n0 + n) * K + k0 + 16 * b;
    *(bf16x8*)(outh + oi) = h0;
    *(bf16x8*)(outh + oi + 8) = h1;
    if constexpr (LO) {
        bf16x8 l0, l1;
#pragma unroll
        for (int i = 0; i < 8; ++i) {
            l0[i] = (bf16_t)(v[i] - (float)h0[i]);
            l1[i] = (bf16_t)(v[8 + i] - (float)h1[i]);
        }
        *(bf16x8*)(outl + oi) = l0;
        *(bf16x8*)(outl + oi + 8) = l1;
    }
}

// ---------------- prep_a: x hi/lo split + Wr1 transpose (gates router1 only) ----------------
#define NCVT2 2048
#define PREP_A_GRID (NCVT2 + 256)

__global__ __launch_bounds__(256) void prep_a_kernel(
    const float* __restrict__ x, const float* __restrict__ Wr1,
    bf16_t* __restrict__ xh, bf16_t* __restrict__ xl,
    bf16_t* __restrict__ Wr1h, bf16_t* __restrict__ Wr1l) {
    __shared__ float4 t[64 * 16];
    int b = blockIdx.x;
    if (b < NCVT2) {                     // x -> hi/lo bf16 split, 32B/lane
        size_t i = (size_t)b * 256 + threadIdx.x;
        const float4* x4 = (const float4*)x;
        float4 v0 = x4[2 * i], v1 = x4[2 * i + 1];
        float f[8] = {v0.x, v0.y, v0.z, v0.w, v1.x, v1.y, v1.z, v1.w};
        bf16x8 h, l;
#pragma unroll
        for (int j = 0; j < 8; ++j) { h[j] = (bf16_t)f[j]; l[j] = (bf16_t)(f[j] - (float)h[j]); }
        *(bf16x8*)(xh + i * 8) = h;
        *(bf16x8*)(xl + i * 8) = l;
        return;
    }
    b -= NCVT2;
    tconv64_body<true>(Wr1, Wr1h, Wr1l, DM, DM, b >> 4, b & 15, t, threadIdx.x);
}

// ---------------- GEMM body (8-wave 2x4, 64x32/wave) — used by r1_fused only ----------------
template<bool SPLIT, bool GATHER, bool GELU, bool SCATTER, bool OUTF32, int BK>
__device__ __forceinline__ void gemm_body(
    const bf16_t* __restrict__ A, const bf16_t* __restrict__ Alo,
    const bf16_t* __restrict__ Bt, const bf16_t* __restrict__ Btlo,
    const float* __restrict__ bias,
    float* __restrict__ outF, bf16_t* __restrict__ outB,
    const int* __restrict__ perm, const int* __restrict__ counts,
    int M, int N, int K, int bx, int by,
    bf16_t* As, bf16_t* Bs, bf16_t* Asl, bf16_t* Bsl) {
    constexpr int NCH = BK / 32;           // 32-k chunks per K-step
    constexpr int CH  = 128 * 32;          // elements per chunk (8KB)
    constexpr int BUF = NCH * CH;          // elements per K-step buffer

    int tile = 0, rb, cnt = M;
    const int* permT = nullptr;
    if constexpr (GATHER) {
        int xb = bx, t = 0, c = 0;
        while (t < NTILES) {
            c = counts[t];
            int nbk = (c + 127) >> 7;
            if (xb < nbk) break;
            xb -= nbk; ++t;
        }
        if (t == NTILES) return;
        tile = t;
        rb = xb * 128;
        cnt = c;
        permT = perm + tile * BATCH;
    } else {
        rb = bx * 128;
    }
    Bt   += (size_t)tile * K * N;
    if constexpr (SPLIT) Btlo += (size_t)tile * K * N;
    bias += (size_t)tile * N;

    const int lane = threadIdx.x & 63;
    const int wave = threadIdx.x >> 6;     // 0..7
    const int wm = wave & 1, wn = wave >> 1;   // 2 x 4 wave grid
    const int nb = by * 128;

    const int srow = lane >> 2;
    const int scol = ((lane & 3) ^ (srow & 3)) * 8;
    const int row = wave * 16 + srow;
    int arow;
    if constexpr (GATHER) {
        int pos = rb + row;
        if (pos > cnt - 1) pos = cnt - 1;
        arow = permT[pos];
    } else {
        arow = rb + row;
    }
    const size_t aoff = (size_t)arow * K + scol;
    const size_t boff = (size_t)(nb + row) * K + scol;

    f32x4 acc[4][2];
#pragma unroll
    for (int i = 0; i < 4; ++i)
#pragma unroll
        for (int j = 0; j < 2; ++j) acc[i][j] = (f32x4){0.f, 0.f, 0.f, 0.f};

    const int lr = lane & 15, lq = lane >> 4;
    const int rdoff = (lr * 4 + (lq ^ (lr & 3))) * 8;

    auto stage = [&](int k0, int buf) {
#pragma unroll
        for (int c = 0; c < NCH; ++c) {
            async_ld16(A  + aoff + k0 + c * 32, &As[buf * BUF + c * CH + wave * 512]);
            async_ld16(Bt + boff + k0 + c * 32, &Bs[buf * BUF + c * CH + wave * 512]);
            if constexpr (SPLIT) {
                async_ld16(Alo  + aoff + k0 + c * 32, &Asl[buf * BUF + c * CH + wave * 512]);
                async_ld16(Btlo + boff + k0 + c * 32, &Bsl[buf * BUF + c * CH + wave * 512]);
            }
        }
    };

    auto compute = [&](int cur) {
#pragma unroll
        for (int kk = 0; kk < NCH; ++kk) {
            const int base = cur * BUF + kk * CH;
            bf16x8 af[4], bfr[2], afl[4], bfl[2];
#pragma unroll
            for (int i = 0; i < 4; ++i) {
                af[i] = *(const bf16x8*)&As[base + (wm * 4 + i) * 512 + rdoff];
                if constexpr (SPLIT)
                    afl[i] = *(const bf16x8*)&Asl[base + (wm * 4 + i) * 512 + rdoff];
            }
#pragma unroll
            for (int j = 0; j < 2; ++j) {
                bfr[j] = *(const bf16x8*)&Bs[base + (wn * 2 + j) * 512 + rdoff];
                if constexpr (SPLIT)
                    bfl[j] = *(const bf16x8*)&Bsl[base + (wn * 2 + j) * 512 + rdoff];
            }
#pragma unroll
            for (int i = 0; i < 4; ++i)
#pragma unroll
                for (int j = 0; j < 2; ++j) {
                    acc[i][j] = mfma16(af[i], bfr[j], acc[i][j]);
                    if constexpr (SPLIT) {
                        acc[i][j] = mfma16(af[i], bfl[j], acc[i][j]);
                        acc[i][j] = mfma16(afl[i], bfr[j], acc[i][j]);
                    }
                }
        }
    };

    stage(0, 0);
    int cur = 0;
    for (int k0 = 0; k0 < K; k0 += BK, cur ^= 1) {
        __syncthreads();
        if (k0 + BK < K) stage(k0 + BK, cur ^ 1);
        compute(cur);
    }

#pragma unroll
    for (int i = 0; i < 4; ++i) {
#pragma unroll
        for (int j = 0; j < 2; ++j) {
#pragma unroll
            for (int r = 0; r < 4; ++r) {
                int m = wm * 64 + i * 16 + lq * 4 + r;
                int n = wn * 32 + j * 16 + lr;
                int pos = rb + m;
                if constexpr (GATHER) { if (pos >= cnt) continue; }
                int grow;
                if constexpr (SCATTER) grow = permT[pos];
                else                   grow = pos;
                int gn = nb + n;
                float v = acc[i][j][r] + bias[gn];
                if constexpr (GELU) v = gelu_exact(v);
                if constexpr (OUTF32) outF[(size_t)grow * N + gn] = v;
                else                  outB[(size_t)grow * N + gn] = (bf16_t)v;
            }
        }
    }
}

// ---------------- fused router1 + W1/W2/Wo transposes (round-6-proven) ----------------
#define NTCONV_TILES (4096 + 4096 + 256)            // W1 + W2 + Wo
#define R1F_GRID (256 + NTCONV_TILES / 2)           // 4480

__global__ __launch_bounds__(512) void r1_fused_kernel(
    const bf16_t* __restrict__ xh, const bf16_t* __restrict__ xl,
    const bf16_t* __restrict__ Wr1h, const bf16_t* __restrict__ Wr1l,
    const float* __restrict__ br1, float* __restrict__ Hr,
    const float* __restrict__ W1, const float* __restrict__ W2,
    const float* __restrict__ Wo,
    bf16_t* __restrict__ W1t, bf16_t* __restrict__ W2t, bf16_t* __restrict__ Wot) {
    __shared__ __align__(16) bf16_t smem[32768];    // 64KB shared by both paths
    const int bid = blockIdx.x;
    if (bid < 256) {
        gemm_body<true, false, true, false, true, 32>(
            xh, xl, Wr1h, Wr1l, br1, Hr, nullptr, nullptr, nullptr,
            BATCH, DM, DM, bid & 31, bid >> 5,
            smem, smem + 8192, smem + 16384, smem + 24576);
        return;
    }
    const int tix = bid - 256;
    const int half = threadIdx.x >> 8;               // 0/1: two tiles per block
    const int tid = threadIdx.x & 255;
    float4* t = (float4*)smem + half * 1024;         // 16KB per half
    const int tile = tix * 2 + half;                 // 0..8447
    if (tile < 4096) {                               // W1: (1024k,2048n), 16kt x 32nt
        int mat = tile >> 9, r = tile & 511;
        size_t off = (size_t)mat * DM * DFF;
        tconv64_body<false>(W1 + off, W1t + off, nullptr, DM, DFF, r >> 5, r & 31, t, tid);
    } else if (tile < 8192) {                        // W2: (2048k,1024n), 32kt x 16nt
        int tt = tile - 4096;
        int mat = tt >> 9, r = tt & 511;
        size_t off = (size_t)mat * DM * DFF;
        tconv64_body<false>(W2 + off, W2t + off, nullptr, DFF, DM, r >> 4, r & 15, t, tid);
    } else {                                         // Wo: 16kt x 16nt
        int r = tile - 8192;
        tconv64_body<false>(Wo, Wot, nullptr, DM, DM, r >> 4, r & 15, t, tid);
    }
}

// ---------------- standalone expert GEMM: 2x2 spatial waves x 2-way K-split ----------------
// NEW: each wave owns a 64x64 sub-tile (af[4] x bf[4] -> 16 MFMA per chunk),
// but only its K-chunk parity h = wave>>2. Per 128x128x64 K-step: 64
// ds_read_b128 (was 96) for the same 128 MFMA — LDS-read time (the measured
// per-CU floor) drops ~33%. Double-buffer loop / staging / swizzle byte-
// identical to the proven structure. After the K-loop the h=1 waves dump
// acc[4][4] into the (now idle) LDS buffers idx-major (lane-stride 16B,
// conflict-free) and the h=0 waves merge + run the proven epilogue.
template<bool GATHER, bool GELU, bool SCATTER, bool OUTF32>
__global__ __launch_bounds__(512) void gemm_ks_kernel(
    const bf16_t* __restrict__ A, const bf16_t* __restrict__ Bt,
    const float* __restrict__ bias,
    float* __restrict__ outF, bf16_t* __restrict__ outB,
    const int* __restrict__ perm, const int* __restrict__ counts,
    int M, int N, int K) {
    constexpr int CH  = 128 * 32;          // elements per 32-k chunk (8KB)
    constexpr int BUF = 2 * CH;            // BK=64 buffer (16KB)
    __shared__ __align__(16) bf16_t As[2 * BUF];    // 32KB
    __shared__ __align__(16) bf16_t Bs[2 * BUF];    // 32KB

    int tile = 0, rb, cnt = M;
    const int* permT = nullptr;
    if constexpr (GATHER) {
        int xb = blockIdx.x, t = 0, c = 0;
        while (t < NTILES) {
            c = counts[t];
            int nbk = (c + 127) >> 7;
            if (xb < nbk) break;
            xb -= nbk; ++t;
        }
        if (t == NTILES) return;
        tile = t;
        rb = xb * 128;
        cnt = c;
        permT = perm + tile * BATCH;
    } else {
        rb = blockIdx.x * 128;
    }
    Bt   += (size_t)tile * K * N;
    bias += (size_t)tile * N;

    const int lane = threadIdx.x & 63;
    const int wave = threadIdx.x >> 6;               // 0..7
    const int wm = wave & 1, wn = (wave >> 1) & 1;   // 2x2 spatial
    const int h  = wave >> 2;                        // K-chunk parity
    const int nb = blockIdx.y * 128;

    // staging (identical map: 8 waves cover 128 rows per chunk)
    const int srow = lane >> 2;
    const int scol = ((lane & 3) ^ (srow & 3)) * 8;
    const int row = wave * 16 + srow;
    int arow;
    if constexpr (GATHER) {
        int pos = rb + row;
        if (pos > cnt - 1) pos = cnt - 1;
        arow = permT[pos];
    } else {
        arow = rb + row;
    }
    const size_t aoff = (size_t)arow * K + scol;
    const size_t boff = (size_t)(nb + row) * K + scol;

    f32x4 acc[4][4];
#pragma unroll
    for (int i = 0; i < 4; ++i)
#pragma unroll
        for (int j = 0; j < 4; ++j) acc[i][j] = (f32x4){0.f, 0.f, 0.f, 0.f};

    const int lr = lane & 15, lq = lane >> 4;
    const int rdoff = (lr * 4 + (lq ^ (lr & 3))) * 8;

    auto stage = [&](int k0, int buf) {
#pragma unroll
        for (int c = 0; c < 2; ++c) {
            async_ld16(A  + aoff + k0 + c * 32, &As[buf * BUF + c * CH + wave * 512]);
            async_ld16(Bt + boff + k0 + c * 32, &Bs[buf * BUF + c * CH + wave * 512]);
        }
    };

    stage(0, 0);
    int cur = 0;
    for (int k0 = 0; k0 < K; k0 += 64, cur ^= 1) {
        __syncthreads();                  // drains vmcnt: buf[cur] ready
        if (k0 + 64 < K) stage(k0 + 64, cur ^ 1);
        const int base = cur * BUF + h * CH;   // my parity's chunk
        bf16x8 af[4], bf[4];
#pragma unroll
        for (int i = 0; i < 4; ++i)
            af[i] = *(const bf16x8*)&As[base + (wm * 4 + i) * 512 + rdoff];
#pragma unroll
        for (int j = 0; j < 4; ++j)
            bf[j] = *(const bf16x8*)&Bs[base + (wn * 4 + j) * 512 + rdoff];
#pragma unroll
        for (int i = 0; i < 4; ++i)
#pragma unroll
            for (int j = 0; j < 4; ++j)
                acc[i][j] = mfma16(af[i], bf[j], acc[i][j]);
    }

    // ---- merge K-split partners via LDS (buffers now idle) ----
    __syncthreads();
    const int region = wn * 2 + wm;                  // 0..3, 16KB each
    float* rbuf = ((region & 2) ? (float*)Bs : (float*)As) + (region & 1) * 4096;
    if (h == 1) {
#pragma unroll
        for (int i = 0; i < 4; ++i)
#pragma unroll
            for (int j = 0; j < 4; ++j)
                *(f32x4*)&rbuf[(i * 4 + j) * 256 + lane * 4] = acc[i][j];
    }
    __syncthreads();
    if (h == 1) return;
#pragma unroll
    for (int i = 0; i < 4; ++i)
#pragma unroll
        for (int j = 0; j < 4; ++j) {
            f32x4 p = *(const f32x4*)&rbuf[(i * 4 + j) * 256 + lane * 4];
            acc[i][j] += p;
        }

    // epilogue (proven mapping): C row = lq*4+reg, col = lr within 16x16 frag
#pragma unroll
    for (int i = 0; i < 4; ++i) {
#pragma unroll
        for (int j = 0; j < 4; ++j) {
#pragma unroll
            for (int r = 0; r < 4; ++r) {
                int m = wm * 64 + i * 16 + lq * 4 + r;
                int n = wn * 64 + j * 16 + lr;
                int pos = rb + m;
                if constexpr (GATHER) { if (pos >= cnt) continue; }
                int grow;
                if constexpr (SCATTER) grow = permT[pos];
                else                   grow = pos;
                int gn = nb + n;
                float v = acc[i][j][r] + bias[gn];
                if constexpr (GELU) v = gelu_exact(v);
                if constexpr (OUTF32) outF[(size_t)grow * N + gn] = v;
                else                  outB[(size_t)grow * N + gn] = (bf16_t)v;
            }
        }
    }
}

// ---------------- router layer2 + argmax + routing lists ----------------
// (unchanged)
__global__ __launch_bounds__(256) void router2_kernel(
    const float* __restrict__ Hr, const float* __restrict__ Wr2, const float* __restrict__ br2,
    float* __restrict__ outLog, float* __restrict__ outIdx,
    int* __restrict__ counts, int* __restrict__ perm) {
    __shared__ float w2s[DM * 9];
    __shared__ int h[NTILES], base[NTILES];
    const int tid = threadIdx.x;
    if (tid < NTILES) h[tid] = 0;
    for (int e = tid; e < DM * 8; e += 256) {
        int k = e >> 3, j = e & 7;
        w2s[k * 9 + j] = Wr2[e];
    }
    __syncthreads();

    const int lane = tid & 63, wave = tid >> 6;
    const int sub = lane >> 4;
    const int lr16 = lane & 15;
    const int row = blockIdx.x * 16 + wave * 4 + sub;

    const float4* Hr4 = (const float4*)Hr;
    float acc[8];
#pragma unroll
    for (int j = 0; j < 8; ++j) acc[j] = 0.f;

#pragma unroll
    for (int i = 0; i < 16; ++i) {
        int f = lr16 + i * 16;
        float4 hv = Hr4[(size_t)row * 256 + f];
        float hx[4] = {hv.x, hv.y, hv.z, hv.w};
        int kbase = f * 4;
#pragma unroll
        for (int d = 0; d < 4; ++d) {
            float xv = hx[d];
            const float* w = &w2s[(kbase + d) * 9];
#pragma unroll
            for (int j = 0; j < 8; ++j) acc[j] += xv * w[j];
        }
    }
#pragma unroll
    for (int off = 8; off; off >>= 1)
#pragma unroll
        for (int j = 0; j < 8; ++j) acc[j] += __shfl_down(acc[j], off);

    int bi = 0, rank = 0;
    if (lr16 == 0) {
        float best = -1e30f;
        float lg[8];
#pragma unroll
        for (int j = 0; j < 8; ++j) {
            float v = (acc[j] + br2[j]) * 2.0f;   // /TEMPERATURE, T=0.5
            lg[j] = v;
            if (v > best) { best = v; bi = j; }   // strict > == first-max (jnp.argmax)
        }
        float4 lo = {lg[0], lg[1], lg[2], lg[3]};
        float4 hi = {lg[4], lg[5], lg[6], lg[7]};
        *(float4*)(outLog + (size_t)row * 8)     = lo;
        *(float4*)(outLog + (size_t)row * 8 + 4) = hi;
        outIdx[row] = (float)bi;
        rank = atomicAdd(&h[bi], 1);
    }
    __syncthreads();
    if (tid < NTILES && h[tid] > 0) base[tid] = atomicAdd(&counts[tid], h[tid]);
    __syncthreads();
    if (lr16 == 0) perm[bi * BATCH + base[bi] + rank] = row;
}

// ---------------- host launch ----------------
extern "C" void kernel_launch(void* const* d_in, const int* in_sizes, int n_in,
                              void* d_out, int out_size, void* d_ws, size_t ws_size,
                              hipStream_t stream) {
    const float* x   = (const float*)d_in[0];
    const float* Wr1 = (const float*)d_in[1];
    const float* br1 = (const float*)d_in[2];
    const float* Wr2 = (const float*)d_in[3];
    const float* br2 = (const float*)d_in[4];
    const float* W1  = (const float*)d_in[5];
    const float* b1  = (const float*)d_in[6];
    const float* W2  = (const float*)d_in[7];
    const float* b2  = (const float*)d_in[8];
    const float* Wo  = (const float*)d_in[9];
    const float* bo  = (const float*)d_in[10];

    char* ws = (char*)d_ws;
    size_t o = 0;
    auto carve = [&](size_t bytes) { char* p = ws + o; o = (o + bytes + 255) & ~(size_t)255; return p; };
    bf16_t* Wr1h = (bf16_t*)carve((size_t)DM * DM * 2);
    bf16_t* Wr1l = (bf16_t*)carve((size_t)DM * DM * 2);
    bf16_t* Wot  = (bf16_t*)carve((size_t)DM * DM * 2);
    bf16_t* W1t  = (bf16_t*)carve((size_t)NTILES * DM * DFF * 2);
    bf16_t* W2t  = (bf16_t*)carve((size_t)NTILES * DM * DFF * 2);
    bf16_t* xh   = (bf16_t*)carve((size_t)BATCH * DM * 2);
    bf16_t* xl   = (bf16_t*)carve((size_t)BATCH * DM * 2);
    bf16_t* H1   = (bf16_t*)carve((size_t)BATCH * DFF * 2);
    bf16_t* sel  = (bf16_t*)carve((size_t)BATCH * DM * 2);
    float*  Hr   = (float*)carve((size_t)BATCH * DM * 4);
    int*    counts = (int*)carve(NTILES * sizeof(int));
    int*    perm   = (int*)carve((size_t)NTILES * BATCH * sizeof(int));

    float* outMain = (float*)d_out;
    float* outIdx  = outMain + (size_t)BATCH * DM;
    float* outLog  = outIdx + BATCH;

    hipMemsetAsync(counts, 0, NTILES * sizeof(int), stream);

    // stage A: only what router1 needs (x split + Wr1 hi/lo transpose)
    prep_a_kernel<<<PREP_A_GRID, 256, 0, stream>>>(x, Wr1, xh, xl, Wr1h, Wr1l);

    // router layer 1 (hi/lo split GEMM) fused with W1/W2/Wo transposes
    r1_fused_kernel<<<R1F_GRID, 512, 0, stream>>>(xh, xl, Wr1h, Wr1l, br1, Hr,
                                                  W1, W2, Wo, W1t, W2t, Wot);

    router2_kernel<<<BATCH / 16, 256, 0, stream>>>(Hr, Wr2, br2, outLog, outIdx, counts, perm);

    // expert layer 1: H1[token] = gelu(x[token] @ W1[t] + b1[t]), gathered+scattered
    gemm_ks_kernel<true, true, true, false><<<dim3(MAXXB, DFF / 128, 1), 512, 0, stream>>>(
        xh, W1t, b1, nullptr, H1, perm, counts, BATCH, DFF, DM);

    // expert layer 2: sel[token] = H1[token] @ W2[t] + b2[t]
    gemm_ks_kernel<true, false, true, false><<<dim3(MAXXB, DM / 128, 1), 512, 0, stream>>>(
        H1, W2t, b2, nullptr, sel, perm, counts, BATCH, DM, DFF);

    // output projection: out = sel @ Wo + bo
    gemm_ks_kernel<false, false, false, true><<<dim3(BATCH / 128, DM / 128, 1), 512, 0, stream>>>(
        sel, Wot, bo, outMain, nullptr, nullptr, nullptr, BATCH, DM, DM);
}

// Round 8
// 351.756 us; speedup vs baseline: 1.1102x; 1.1102x over previous
//
#include <hip/hip_runtime.h>
#include <hip/hip_bf16.h>
#include <math.h>
#include <stdint.h>

typedef __bf16 bf16_t;
typedef __bf16 bf16x8 __attribute__((ext_vector_type(8)));
typedef float  f32x4  __attribute__((ext_vector_type(4)));

#define BATCH   4096
#define DM      1024
#define DFF     2048
#define NTILES  8
#define MAXXB   40   // max compacted x-blocks: 32 + 7 partials

__device__ __forceinline__ float gelu_exact(float x) {
    return 0.5f * x * (1.0f + erff(x * 0.70710678118654752440f));
}

__device__ __forceinline__ void async_ld16(const bf16_t* g, bf16_t* l) {
    __builtin_amdgcn_global_load_lds(
        (const __attribute__((address_space(1))) void*)g,
        (__attribute__((address_space(3))) void*)l, 16, 0, 0);
}

__device__ __forceinline__ f32x4 mfma16(bf16x8 a, bf16x8 b, f32x4 c) {
    return __builtin_amdgcn_mfma_f32_16x16x32_bf16(a, b, c, 0, 0, 0);
}

// ---------------- 64x64 transpose+convert tile (round-1-proven math) ----------------
template<bool LO>
__device__ void tconv64_body(const float* __restrict__ src, bf16_t* __restrict__ outh,
                             bf16_t* __restrict__ outl, int K, int N, int kt, int nt,
                             float4* t /* 64*16 float4 = 16KB */, int tid) {
    const int k0 = kt * 64, n0 = nt * 64;
#pragma unroll
    for (int p = 0; p < 4; ++p) {
        int row = p * 16 + (tid >> 4);
        int c = tid & 15;
        float4 v = *(const float4*)(src + (size_t)(k0 + row) * N + n0 + c * 4);
        t[row * 16 + (c ^ ((row >> 2) & 15))] = v;
    }
    __syncthreads();
    const int n = tid >> 2, b = tid & 3;
    const float* tf = (const float*)t;
    float v[16];
#pragma unroll
    for (int i = 0; i < 16; ++i) {
        int k = 16 * b + i;
        int f4 = k * 16 + ((n >> 2) ^ ((k >> 2) & 15));
        v[i] = tf[f4 * 4 + (n & 3)];
    }
    bf16x8 h0, h1;
#pragma unroll
    for (int i = 0; i < 8; ++i) { h0[i] = (bf16_t)v[i]; h1[i] = (bf16_t)v[8 + i]; }
    size_t oi = (size_t)(n0 + n) * K + k0 + 16 * b;
    *(bf16x8*)(outh + oi) = h0;
    *(bf16x8*)(outh + oi + 8) = h1;
    if constexpr (LO) {
        bf16x8 l0, l1;
#pragma unroll
        for (int i = 0; i < 8; ++i) {
            l0[i] = (bf16_t)(v[i] - (float)h0[i]);
            l1[i] = (bf16_t)(v[8 + i] - (float)h1[i]);
        }
        *(bf16x8*)(outl + oi) = l0;
        *(bf16x8*)(outl + oi + 8) = l1;
    }
}

// ---------------- prep_a: x hi/lo split + Wr1 transpose (gates router1 only) ----------------
#define NCVT2 2048
#define PREP_A_GRID (NCVT2 + 256)

__global__ __launch_bounds__(256) void prep_a_kernel(
    const float* __restrict__ x, const float* __restrict__ Wr1,
    bf16_t* __restrict__ xh, bf16_t* __restrict__ xl,
    bf16_t* __restrict__ Wr1h, bf16_t* __restrict__ Wr1l) {
    __shared__ float4 t[64 * 16];
    int b = blockIdx.x;
    if (b < NCVT2) {                     // x -> hi/lo bf16 split, 32B/lane
        size_t i = (size_t)b * 256 + threadIdx.x;
        const float4* x4 = (const float4*)x;
        float4 v0 = x4[2 * i], v1 = x4[2 * i + 1];
        float f[8] = {v0.x, v0.y, v0.z, v0.w, v1.x, v1.y, v1.z, v1.w};
        bf16x8 h, l;
#pragma unroll
        for (int j = 0; j < 8; ++j) { h[j] = (bf16_t)f[j]; l[j] = (bf16_t)(f[j] - (float)h[j]); }
        *(bf16x8*)(xh + i * 8) = h;
        *(bf16x8*)(xl + i * 8) = l;
        return;
    }
    b -= NCVT2;
    tconv64_body<true>(Wr1, Wr1h, Wr1l, DM, DM, b >> 4, b & 15, t, threadIdx.x);
}

// ---------------- GEMM body (8-wave 2x4, 64x32/wave) — used by r1_fused only ----------------
template<bool SPLIT, bool GATHER, bool GELU, bool SCATTER, bool OUTF32, int BK>
__device__ __forceinline__ void gemm_body(
    const bf16_t* __restrict__ A, const bf16_t* __restrict__ Alo,
    const bf16_t* __restrict__ Bt, const bf16_t* __restrict__ Btlo,
    const float* __restrict__ bias,
    float* __restrict__ outF, bf16_t* __restrict__ outB,
    const int* __restrict__ perm, const int* __restrict__ counts,
    int M, int N, int K, int bx, int by,
    bf16_t* As, bf16_t* Bs, bf16_t* Asl, bf16_t* Bsl) {
    constexpr int NCH = BK / 32;           // 32-k chunks per K-step
    constexpr int CH  = 128 * 32;          // elements per chunk (8KB)
    constexpr int BUF = NCH * CH;          // elements per K-step buffer

    int tile = 0, rb, cnt = M;
    const int* permT = nullptr;
    if constexpr (GATHER) {
        int xb = bx, t = 0, c = 0;
        while (t < NTILES) {
            c = counts[t];
            int nbk = (c + 127) >> 7;
            if (xb < nbk) break;
            xb -= nbk; ++t;
        }
        if (t == NTILES) return;
        tile = t;
        rb = xb * 128;
        cnt = c;
        permT = perm + tile * BATCH;
    } else {
        rb = bx * 128;
    }
    Bt   += (size_t)tile * K * N;
    if constexpr (SPLIT) Btlo += (size_t)tile * K * N;
    bias += (size_t)tile * N;

    const int lane = threadIdx.x & 63;
    const int wave = threadIdx.x >> 6;     // 0..7
    const int wm = wave & 1, wn = wave >> 1;   // 2 x 4 wave grid
    const int nb = by * 128;

    const int srow = lane >> 2;
    const int scol = ((lane & 3) ^ (srow & 3)) * 8;
    const int row = wave * 16 + srow;
    int arow;
    if constexpr (GATHER) {
        int pos = rb + row;
        if (pos > cnt - 1) pos = cnt - 1;
        arow = permT[pos];
    } else {
        arow = rb + row;
    }
    const size_t aoff = (size_t)arow * K + scol;
    const size_t boff = (size_t)(nb + row) * K + scol;

    f32x4 acc[4][2];
#pragma unroll
    for (int i = 0; i < 4; ++i)
#pragma unroll
        for (int j = 0; j < 2; ++j) acc[i][j] = (f32x4){0.f, 0.f, 0.f, 0.f};

    const int lr = lane & 15, lq = lane >> 4;
    const int rdoff = (lr * 4 + (lq ^ (lr & 3))) * 8;

    auto stage = [&](int k0, int buf) {
#pragma unroll
        for (int c = 0; c < NCH; ++c) {
            async_ld16(A  + aoff + k0 + c * 32, &As[buf * BUF + c * CH + wave * 512]);
            async_ld16(Bt + boff + k0 + c * 32, &Bs[buf * BUF + c * CH + wave * 512]);
            if constexpr (SPLIT) {
                async_ld16(Alo  + aoff + k0 + c * 32, &Asl[buf * BUF + c * CH + wave * 512]);
                async_ld16(Btlo + boff + k0 + c * 32, &Bsl[buf * BUF + c * CH + wave * 512]);
            }
        }
    };

    auto compute = [&](int cur) {
#pragma unroll
        for (int kk = 0; kk < NCH; ++kk) {
            const int base = cur * BUF + kk * CH;
            bf16x8 af[4], bfr[2], afl[4], bfl[2];
#pragma unroll
            for (int i = 0; i < 4; ++i) {
                af[i] = *(const bf16x8*)&As[base + (wm * 4 + i) * 512 + rdoff];
                if constexpr (SPLIT)
                    afl[i] = *(const bf16x8*)&Asl[base + (wm * 4 + i) * 512 + rdoff];
            }
#pragma unroll
            for (int j = 0; j < 2; ++j) {
                bfr[j] = *(const bf16x8*)&Bs[base + (wn * 2 + j) * 512 + rdoff];
                if constexpr (SPLIT)
                    bfl[j] = *(const bf16x8*)&Bsl[base + (wn * 2 + j) * 512 + rdoff];
            }
#pragma unroll
            for (int i = 0; i < 4; ++i)
#pragma unroll
                for (int j = 0; j < 2; ++j) {
                    acc[i][j] = mfma16(af[i], bfr[j], acc[i][j]);
                    if constexpr (SPLIT) {
                        acc[i][j] = mfma16(af[i], bfl[j], acc[i][j]);
                        acc[i][j] = mfma16(afl[i], bfr[j], acc[i][j]);
                    }
                }
        }
    };

    stage(0, 0);
    int cur = 0;
    for (int k0 = 0; k0 < K; k0 += BK, cur ^= 1) {
        __syncthreads();
        if (k0 + BK < K) stage(k0 + BK, cur ^ 1);
        compute(cur);
    }

#pragma unroll
    for (int i = 0; i < 4; ++i) {
#pragma unroll
        for (int j = 0; j < 2; ++j) {
#pragma unroll
            for (int r = 0; r < 4; ++r) {
                int m = wm * 64 + i * 16 + lq * 4 + r;
                int n = wn * 32 + j * 16 + lr;
                int pos = rb + m;
                if constexpr (GATHER) { if (pos >= cnt) continue; }
                int grow;
                if constexpr (SCATTER) grow = permT[pos];
                else                   grow = pos;
                int gn = nb + n;
                float v = acc[i][j][r] + bias[gn];
                if constexpr (GELU) v = gelu_exact(v);
                if constexpr (OUTF32) outF[(size_t)grow * N + gn] = v;
                else                  outB[(size_t)grow * N + gn] = (bf16_t)v;
            }
        }
    }
}

// ---------------- fused router1 + W1/W2/Wo transposes (round-6-proven) ----------------
#define NTCONV_TILES (4096 + 4096 + 256)            // W1 + W2 + Wo
#define R1F_GRID (256 + NTCONV_TILES / 2)           // 4480

__global__ __launch_bounds__(512) void r1_fused_kernel(
    const bf16_t* __restrict__ xh, const bf16_t* __restrict__ xl,
    const bf16_t* __restrict__ Wr1h, const bf16_t* __restrict__ Wr1l,
    const float* __restrict__ br1, float* __restrict__ Hr,
    const float* __restrict__ W1, const float* __restrict__ W2,
    const float* __restrict__ Wo,
    bf16_t* __restrict__ W1t, bf16_t* __restrict__ W2t, bf16_t* __restrict__ Wot) {
    __shared__ __align__(16) bf16_t smem[32768];    // 64KB shared by both paths
    const int bid = blockIdx.x;
    if (bid < 256) {
        gemm_body<true, false, true, false, true, 32>(
            xh, xl, Wr1h, Wr1l, br1, Hr, nullptr, nullptr, nullptr,
            BATCH, DM, DM, bid & 31, bid >> 5,
            smem, smem + 8192, smem + 16384, smem + 24576);
        return;
    }
    const int tix = bid - 256;
    const int half = threadIdx.x >> 8;               // 0/1: two tiles per block
    const int tid = threadIdx.x & 255;
    float4* t = (float4*)smem + half * 1024;         // 16KB per half
    const int tile = tix * 2 + half;                 // 0..8447
    if (tile < 4096) {                               // W1: (1024k,2048n), 16kt x 32nt
        int mat = tile >> 9, r = tile & 511;
        size_t off = (size_t)mat * DM * DFF;
        tconv64_body<false>(W1 + off, W1t + off, nullptr, DM, DFF, r >> 5, r & 31, t, tid);
    } else if (tile < 8192) {                        // W2: (2048k,1024n), 32kt x 16nt
        int tt = tile - 4096;
        int mat = tt >> 9, r = tt & 511;
        size_t off = (size_t)mat * DM * DFF;
        tconv64_body<false>(W2 + off, W2t + off, nullptr, DFF, DM, r >> 4, r & 15, t, tid);
    } else {                                         // Wo: 16kt x 16nt
        int r = tile - 8192;
        tconv64_body<false>(Wo, Wot, nullptr, DM, DM, r >> 4, r & 15, t, tid);
    }
}

// ---------------- expert GEMM: m97-config 4-wave / 256-thread blocks ----------------
// REVERT of the round-1 8-wave switch (never isolated; round-7 showed the
// expert plateau is TLP-starved latency). 128x128 tile, BK=32, 4 waves (2x2:
// wave tile 64x64 -> 8 ds_read_b128 per 16 MFMA, intensity 2.0), 32KB LDS ->
// ~4 blocks/CU co-resident (vs 2): doubled block-level TLP interleaves the
// per-K-step HBM drains. Staging/swizzle/epilogue = round-0-proven math;
// gather = counts-walk (round-6-proven).
template<bool GATHER, bool GELU, bool SCATTER, bool OUTF32>
__global__ __launch_bounds__(256) void gemm4w_kernel(
    const bf16_t* __restrict__ A, const bf16_t* __restrict__ Bt,
    const float* __restrict__ bias,
    float* __restrict__ outF, bf16_t* __restrict__ outB,
    const int* __restrict__ perm, const int* __restrict__ counts,
    int M, int N, int K) {
    constexpr int BUF = 128 * 32;          // 4096 elements = 8KB per buffer
    __shared__ __align__(16) bf16_t As[2 * BUF];    // 16KB
    __shared__ __align__(16) bf16_t Bs[2 * BUF];    // 16KB

    int tile = 0, rb, cnt = M;
    const int* permT = nullptr;
    if constexpr (GATHER) {
        int xb = blockIdx.x, t = 0, c = 0;
        while (t < NTILES) {
            c = counts[t];
            int nbk = (c + 127) >> 7;
            if (xb < nbk) break;
            xb -= nbk; ++t;
        }
        if (t == NTILES) return;          // beyond total routed blocks (uniform)
        tile = t;
        rb = xb * 128;
        cnt = c;
        permT = perm + tile * BATCH;
    } else {
        rb = blockIdx.x * 128;
    }
    Bt   += (size_t)tile * K * N;
    bias += (size_t)tile * N;

    const int lane = threadIdx.x & 63;
    const int wave = threadIdx.x >> 6;     // 0..3
    const int wm = wave & 1, wn = wave >> 1;   // 2 x 2 wave grid
    const int nb = blockIdx.y * 128;

    // staging: 2 reps x 4 waves cover 128 rows; one 16B lane-load per rep per matrix
    const int srow = lane >> 2;                       // 0..15 within 16-row segment
    const int scol = ((lane & 3) ^ (srow & 3)) * 8;   // swizzled k-chunk (elements)
    size_t aoff[2], boff[2];
#pragma unroll
    for (int r = 0; r < 2; ++r) {
        int seg = r * 4 + wave;
        int row = seg * 16 + srow;
        int arow;
        if constexpr (GATHER) {
            int pos = rb + row;
            if (pos > cnt - 1) pos = cnt - 1;
            arow = permT[pos];
        } else {
            arow = rb + row;
        }
        aoff[r] = (size_t)arow * K + scol;
        boff[r] = (size_t)(nb + row) * K + scol;
    }

    f32x4 acc[4][4];
#pragma unroll
    for (int i = 0; i < 4; ++i)
#pragma unroll
        for (int j = 0; j < 4; ++j) acc[i][j] = (f32x4){0.f, 0.f, 0.f, 0.f};

    const int lr = lane & 15, lq = lane >> 4;
    const int rdoff = (lr * 4 + (lq ^ (lr & 3))) * 8;

    auto stage = [&](int k0, int buf) {
#pragma unroll
        for (int r = 0; r < 2; ++r) {
            int seg = r * 4 + wave;
            async_ld16(A  + aoff[r] + k0, &As[buf * BUF + seg * 512]);
            async_ld16(Bt + boff[r] + k0, &Bs[buf * BUF + seg * 512]);
        }
    };

    stage(0, 0);
    int cur = 0;
    for (int k0 = 0; k0 < K; k0 += 32, cur ^= 1) {
        __syncthreads();                  // drains vmcnt: buf[cur] ready
        if (k0 + 32 < K) stage(k0 + 32, cur ^ 1);
        bf16x8 af[4], bf[4];
#pragma unroll
        for (int i = 0; i < 4; ++i)
            af[i] = *(const bf16x8*)&As[cur * BUF + (wm * 4 + i) * 512 + rdoff];
#pragma unroll
        for (int j = 0; j < 4; ++j)
            bf[j] = *(const bf16x8*)&Bs[cur * BUF + (wn * 4 + j) * 512 + rdoff];
#pragma unroll
        for (int i = 0; i < 4; ++i)
#pragma unroll
            for (int j = 0; j < 4; ++j)
                acc[i][j] = mfma16(af[i], bf[j], acc[i][j]);
    }

    // epilogue: C row = (lane>>4)*4 + reg, col = lane&15 (m89/m91-verified)
#pragma unroll
    for (int i = 0; i < 4; ++i) {
#pragma unroll
        for (int j = 0; j < 4; ++j) {
#pragma unroll
            for (int r = 0; r < 4; ++r) {
                int m = wm * 64 + i * 16 + lq * 4 + r;
                int n = wn * 64 + j * 16 + lr;
                int pos = rb + m;
                if constexpr (GATHER) { if (pos >= cnt) continue; }
                int grow;
                if constexpr (SCATTER) grow = permT[pos];
                else                   grow = pos;
                int gn = nb + n;
                float v = acc[i][j][r] + bias[gn];
                if constexpr (GELU) v = gelu_exact(v);
                if constexpr (OUTF32) outF[(size_t)grow * N + gn] = v;
                else                  outB[(size_t)grow * N + gn] = (bf16_t)v;
            }
        }
    }
}

// ---------------- router layer2 + argmax + routing lists ----------------
// (unchanged)
__global__ __launch_bounds__(256) void router2_kernel(
    const float* __restrict__ Hr, const float* __restrict__ Wr2, const float* __restrict__ br2,
    float* __restrict__ outLog, float* __restrict__ outIdx,
    int* __restrict__ counts, int* __restrict__ perm) {
    __shared__ float w2s[DM * 9];
    __shared__ int h[NTILES], base[NTILES];
    const int tid = threadIdx.x;
    if (tid < NTILES) h[tid] = 0;
    for (int e = tid; e < DM * 8; e += 256) {
        int k = e >> 3, j = e & 7;
        w2s[k * 9 + j] = Wr2[e];
    }
    __syncthreads();

    const int lane = tid & 63, wave = tid >> 6;
    const int sub = lane >> 4;
    const int lr16 = lane & 15;
    const int row = blockIdx.x * 16 + wave * 4 + sub;

    const float4* Hr4 = (const float4*)Hr;
    float acc[8];
#pragma unroll
    for (int j = 0; j < 8; ++j) acc[j] = 0.f;

#pragma unroll
    for (int i = 0; i < 16; ++i) {
        int f = lr16 + i * 16;
        float4 hv = Hr4[(size_t)row * 256 + f];
        float hx[4] = {hv.x, hv.y, hv.z, hv.w};
        int kbase = f * 4;
#pragma unroll
        for (int d = 0; d < 4; ++d) {
            float xv = hx[d];
            const float* w = &w2s[(kbase + d) * 9];
#pragma unroll
            for (int j = 0; j < 8; ++j) acc[j] += xv * w[j];
        }
    }
#pragma unroll
    for (int off = 8; off; off >>= 1)
#pragma unroll
        for (int j = 0; j < 8; ++j) acc[j] += __shfl_down(acc[j], off);

    int bi = 0, rank = 0;
    if (lr16 == 0) {
        float best = -1e30f;
        float lg[8];
#pragma unroll
        for (int j = 0; j < 8; ++j) {
            float v = (acc[j] + br2[j]) * 2.0f;   // /TEMPERATURE, T=0.5
            lg[j] = v;
            if (v > best) { best = v; bi = j; }   // strict > == first-max (jnp.argmax)
        }
        float4 lo = {lg[0], lg[1], lg[2], lg[3]};
        float4 hi = {lg[4], lg[5], lg[6], lg[7]};
        *(float4*)(outLog + (size_t)row * 8)     = lo;
        *(float4*)(outLog + (size_t)row * 8 + 4) = hi;
        outIdx[row] = (float)bi;
        rank = atomicAdd(&h[bi], 1);
    }
    __syncthreads();
    if (tid < NTILES && h[tid] > 0) base[tid] = atomicAdd(&counts[tid], h[tid]);
    __syncthreads();
    if (lr16 == 0) perm[bi * BATCH + base[bi] + rank] = row;
}

// ---------------- host launch ----------------
extern "C" void kernel_launch(void* const* d_in, const int* in_sizes, int n_in,
                              void* d_out, int out_size, void* d_ws, size_t ws_size,
                              hipStream_t stream) {
    const float* x   = (const float*)d_in[0];
    const float* Wr1 = (const float*)d_in[1];
    const float* br1 = (const float*)d_in[2];
    const float* Wr2 = (const float*)d_in[3];
    const float* br2 = (const float*)d_in[4];
    const float* W1  = (const float*)d_in[5];
    const float* b1  = (const float*)d_in[6];
    const float* W2  = (const float*)d_in[7];
    const float* b2  = (const float*)d_in[8];
    const float* Wo  = (const float*)d_in[9];
    const float* bo  = (const float*)d_in[10];

    char* ws = (char*)d_ws;
    size_t o = 0;
    auto carve = [&](size_t bytes) { char* p = ws + o; o = (o + bytes + 255) & ~(size_t)255; return p; };
    bf16_t* Wr1h = (bf16_t*)carve((size_t)DM * DM * 2);
    bf16_t* Wr1l = (bf16_t*)carve((size_t)DM * DM * 2);
    bf16_t* Wot  = (bf16_t*)carve((size_t)DM * DM * 2);
    bf16_t* W1t  = (bf16_t*)carve((size_t)NTILES * DM * DFF * 2);
    bf16_t* W2t  = (bf16_t*)carve((size_t)NTILES * DM * DFF * 2);
    bf16_t* xh   = (bf16_t*)carve((size_t)BATCH * DM * 2);
    bf16_t* xl   = (bf16_t*)carve((size_t)BATCH * DM * 2);
    bf16_t* H1   = (bf16_t*)carve((size_t)BATCH * DFF * 2);
    bf16_t* sel  = (bf16_t*)carve((size_t)BATCH * DM * 2);
    float*  Hr   = (float*)carve((size_t)BATCH * DM * 4);
    int*    counts = (int*)carve(NTILES * sizeof(int));
    int*    perm   = (int*)carve((size_t)NTILES * BATCH * sizeof(int));

    float* outMain = (float*)d_out;
    float* outIdx  = outMain + (size_t)BATCH * DM;
    float* outLog  = outIdx + BATCH;

    hipMemsetAsync(counts, 0, NTILES * sizeof(int), stream);

    // stage A: only what router1 needs (x split + Wr1 hi/lo transpose)
    prep_a_kernel<<<PREP_A_GRID, 256, 0, stream>>>(x, Wr1, xh, xl, Wr1h, Wr1l);

    // router layer 1 (hi/lo split GEMM) fused with W1/W2/Wo transposes
    r1_fused_kernel<<<R1F_GRID, 512, 0, stream>>>(xh, xl, Wr1h, Wr1l, br1, Hr,
                                                  W1, W2, Wo, W1t, W2t, Wot);

    router2_kernel<<<BATCH / 16, 256, 0, stream>>>(Hr, Wr2, br2, outLog, outIdx, counts, perm);

    // expert layer 1: H1[token] = gelu(x[token] @ W1[t] + b1[t]), gathered+scattered
    gemm4w_kernel<true, true, true, false><<<dim3(MAXXB, DFF / 128, 1), 256, 0, stream>>>(
        xh, W1t, b1, nullptr, H1, perm, counts, BATCH, DFF, DM);

    // expert layer 2: sel[token] = H1[token] @ W2[t] + b2[t]
    gemm4w_kernel<true, false, true, false><<<dim3(MAXXB, DM / 128, 1), 256, 0, stream>>>(
        H1, W2t, b2, nullptr, sel, perm, counts, BATCH, DM, DFF);

    // output projection: out = sel @ Wo + bo
    gemm4w_kernel<false, false, false, true><<<dim3(BATCH / 128, DM / 128, 1), 256, 0, stream>>>(
        sel, Wot, bo, outMain, nullptr, nullptr, nullptr, BATCH, DM, DM);
}